// Round 1
// baseline (195.048 us; speedup 1.0000x reference)
//
#include <hip/hip_runtime.h>

typedef unsigned short u16;
typedef unsigned int u32;

typedef float f4 __attribute__((ext_vector_type(4)));
typedef short s8v __attribute__((ext_vector_type(8)));
typedef u16 us8 __attribute__((ext_vector_type(8)));
typedef _Float16 h4 __attribute__((ext_vector_type(4)));

__device__ __forceinline__ u16 f2bf(float x){ u32 b=__float_as_uint(x); b += 0x7FFFu + ((b>>16)&1u); return (u16)(b>>16); }
__device__ __forceinline__ float bf2f(u16 u){ return __uint_as_float(((u32)u)<<16); }
__device__ __forceinline__ u16 f2h(float x){ union{_Float16 h; u16 u;} c; c.h=(_Float16)x; return c.u; }
__device__ __forceinline__ _Float16 u2h(u16 u){ union{u16 u; _Float16 h;} c; c.u=u; return c.h; }

// ---- workspace byte offsets ----
#define O_XR   4096u        // bf16 xr [4][256][1024]            2,097,152 B
#define O_WPT  2101248u     // bf16 Wp^T 4 classes [192][Kp]       884,736 B
#define O_QH   2985984u     // f16 q (pre-scaled) [4][64][4225]  2,163,200 B
#define O_KT   5149184u     // f16 k^T [4][8][1024][8]             524,288 B
#define O_V    5673472u     // f16 v [4][64][1024]                 524,288 B
#define O_ATT  6197760u     // f32 attnout [4][64][4225]         4,326,400 B
#define O_WKT  10524160u    // f32 w_k^T [256][64]
#define O_WVT  10589696u    // f32 w_v^T [256][64]
#define O_WOT  10655232u    // f32 w_o^T [64][128]   (end 10,688,000)

// =================== K1: BN+ReLU + weight re-layouts ===================
__global__ __launch_bounds__(256) void k_prep(
    const float* __restrict__ x, const float* __restrict__ gamma, const float* __restrict__ beta,
    const float* __restrict__ mean, const float* __restrict__ var,
    const float* __restrict__ w_sc, const float* __restrict__ w_q,
    const float* __restrict__ w_k, const float* __restrict__ w_v, const float* __restrict__ w_o,
    u16* __restrict__ xr, u16* __restrict__ wpt,
    float* __restrict__ wkT, float* __restrict__ wvT, float* __restrict__ woT)
{
  int bi = blockIdx.x;
  int tid = threadIdx.x;
  if (bi < 1024) {                       // BN+ReLU: one (b,c) row per block
    int b = bi >> 8, c = bi & 255;
    float inv = rsqrtf(var[c] + 1e-5f);
    float s = gamma[c] * inv;
    float sh = beta[c] - mean[c] * s;
    const float4* xp = (const float4*)(x + (size_t)(b*256 + c)*1024);
    ushort4* op = (ushort4*)(xr + (size_t)(b*256 + c)*1024);
    float4 v = xp[tid];
    ushort4 o;
    o.x = f2bf(fmaxf(v.x*s + sh, 0.f));
    o.y = f2bf(fmaxf(v.y*s + sh, 0.f));
    o.z = f2bf(fmaxf(v.z*s + sh, 0.f));
    o.w = f2bf(fmaxf(v.w*s + sh, 0.f));
    op[tid] = o;
    return;
  }
  int wid = (bi - 1024)*256 + tid;
  if (wid < 442368) {
    // jax conv_transpose (no kernel flip): scatter offset kys=py+2dy uses w[2-kys].
    // Inverse map from source (ky,kx): ky=0 -> (py=0,dy=1); ky=1 -> (py=1,dy=0); ky=2 -> (py=0,dy=0)
    int c, m, ky, kx; float val;
    if (wid < 294912) {
      c = wid / 1152; int r = wid - c*1152; m = r / 9; int t9 = r - m*9; ky = t9/3; kx = t9 - ky*3;
      val = w_sc[wid];
    } else {
      int i2 = wid - 294912;
      c = i2 / 576; int r = i2 - c*576; m = r / 9; int t9 = r - m*9; ky = t9/3; kx = t9 - ky*3;
      val = w_q[i2] * 0.51007023f;   // fold log2(e)/sqrt(8) into q weights
      m += 128;
    }
    int py = (ky==1) ? 1 : 0; int dy = (ky==0) ? 1 : 0;
    int px = (kx==1) ? 1 : 0; int dx = (kx==0) ? 1 : 0;
    int cls = py*2 + px;
    int tt, KP, base;
    if (cls==0){ tt = dy*2+dx; KP=1024; base=0; }
    else if (cls==1){ tt = dy; KP=512; base=196608; }
    else if (cls==2){ tt = dx; KP=512; base=294912; }
    else { tt = 0; KP=256; base=393216; }
    wpt[base + m*KP + tt*256 + c] = f2bf(val);
  } else if (wid < 458752) {
    int i = wid - 442368; int c = i >> 6, d = i & 63;
    wkT[c*64 + d] = w_k[d*256 + c];
  } else if (wid < 475136) {
    int i = wid - 458752; int c = i >> 6, d = i & 63;
    wvT[c*64 + d] = w_v[d*256 + c];
  } else if (wid < 483328) {
    int i = wid - 475136; int d = i >> 7, o = i & 127;
    woT[d*128 + o] = w_o[o*64 + d];
  }
}

// =================== K2: conv-transpose GEMM (MFMA) + k/v ===================
template<int PY,int PX,int TT>
__device__ __forceinline__ void conv_cls(
    const u16* __restrict__ xr, const u16* __restrict__ wcls,
    float* __restrict__ outF, u16* __restrict__ qh,
    int mb, int nb, u16* Blds)
{
  constexpr int Hy = 33 - PY, Wx = 33 - PX;
  constexpr int NC = 4*Hy*Wx;
  constexpr int KP = TT*256;
  constexpr int NKT = KP/32;
  int tid = threadIdx.x;
  int lane = tid & 63, wv = tid >> 6, quad = lane >> 4, c15 = lane & 15;
  int sn = tid >> 2, sg = tid & 3;
  int n_g = nb*64 + sn;
  bool nv = n_g < NC;
  int bb=0, yq=0, xq=0;
  if (nv) { bb = n_g/(Hy*Wx); int rem = n_g - bb*(Hy*Wx); yq = rem/Wx; xq = rem - yq*Wx; }
  f4 acc[4];
  #pragma unroll
  for (int i=0;i<4;i++) acc[i] = (f4){0.f,0.f,0.f,0.f};
  const u16* arow = wcls + (size_t)(mb*64 + wv*16 + c15)*KP + quad*8;
  for (int kt = 0; kt < NKT; ++kt) {
    int tt = kt >> 3;
    int cb = (kt & 7) * 32;
    int dy, dx;
    if (TT==4){ dy = tt>>1; dx = tt&1; }
    else if (TT==2){ if (PX==1){ dy=tt; dx=0; } else { dy=0; dx=tt; } }
    else { dy=0; dx=0; }
    int ii = yq - dy, jj = xq - dx;
    bool ok = nv && (ii>=0) && (ii<32) && (jj>=0) && (jj<32);
    int off = ((bb*256 + cb + sg*8) << 10) + ii*32 + jj;
    us8 vals;
    #pragma unroll
    for (int r=0;r<8;r++) vals[r] = ok ? xr[off + (r<<10)] : (u16)0;
    __syncthreads();
    *(us8*)(Blds + sn*40 + sg*8) = vals;       // B-LDS [n][k], stride 40
    __syncthreads();
    s8v a = *(const s8v*)(arow + kt*32);       // A direct from global (L2-resident)
    #pragma unroll
    for (int t4=0;t4<4;t4++) {
      s8v bf = *(const s8v*)(Blds + (t4*16 + c15)*40 + quad*8);
      acc[t4] = __builtin_amdgcn_mfma_f32_16x16x32_bf16(a, bf, acc[t4], 0, 0, 0);
    }
  }
  int mrow = mb*64 + wv*16 + quad*4;
  #pragma unroll
  for (int t4=0;t4<4;t4++) {
    int n2 = nb*64 + t4*16 + c15;
    if (n2 < NC) {
      int bb2 = n2/(Hy*Wx); int rem = n2 - bb2*(Hy*Wx); int yq2 = rem/Wx; int xq2 = rem - yq2*Wx;
      int pix = (2*yq2 + PY)*65 + (2*xq2 + PX);
      #pragma unroll
      for (int rg=0; rg<4; rg++) {
        int m = mrow + rg;
        float vvv = acc[t4][rg];
        if (m < 128) outF[(size_t)(bb2*128 + m)*4225 + pix] = vvv;
        else qh[(size_t)(bb2*64 + (m-128))*4225 + pix] = f2h(vvv);
      }
    }
  }
}

__global__ __launch_bounds__(256) void k_conv_kv(
    const u16* __restrict__ xr, const u16* __restrict__ wpt,
    const float* __restrict__ wkT, const float* __restrict__ wvT,
    float* __restrict__ outF, u16* __restrict__ qh,
    u16* __restrict__ kT, u16* __restrict__ vbuf)
{
  __shared__ __align__(16) u16 Blds[64*40];
  int bi = blockIdx.x;
  if (bi < 795) {
    int mb = bi % 3, cy = bi / 3;
    if (cy < 69)       conv_cls<0,0,4>(xr, wpt,          outF, qh, mb, cy,     Blds);
    else if (cy < 135) conv_cls<0,1,2>(xr, wpt + 196608, outF, qh, mb, cy-69,  Blds);
    else if (cy < 201) conv_cls<1,0,2>(xr, wpt + 294912, outF, qh, mb, cy-135, Blds);
    else               conv_cls<1,1,1>(xr, wpt + 393216, outF, qh, mb, cy-201, Blds);
  } else {
    int kid = bi - 795;
    int ntile = kid & 3, chunk = (kid >> 2) & 15, b = kid >> 6;
    int n = ntile*256 + threadIdx.x;
    bool isV = chunk >= 8;
    int dbase = (chunk & 7) * 8;
    const float* wT = isV ? wvT : wkT;     // [256][64]
    float acc[8];
    #pragma unroll
    for (int r=0;r<8;r++) acc[r]=0.f;
    const u16* xp = xr + ((size_t)b << 18) + n;
    for (int c=0;c<256;c++) {
      float xv = bf2f(xp[(size_t)c<<10]);
      const float* wr = wT + c*64 + dbase;   // uniform -> scalar loads
      #pragma unroll
      for (int r=0;r<8;r++) acc[r] += wr[r]*xv;
    }
    if (!isV) {
      us8 pk;
      #pragma unroll
      for (int r=0;r<8;r++) pk[r] = f2h(acc[r]);
      *(us8*)(kT + ((size_t)(b*8 + chunk)*1024 + n)*8) = pk;   // k^T [key][d]
    } else {
      int dv0 = (chunk-8)*8;
      #pragma unroll
      for (int r=0;r<8;r++) vbuf[(size_t)(b*64 + dv0 + r)*1024 + n] = f2h(acc[r]);
    }
  }
}

// =================== K3: attention (S^T trick, 2-pass softmax) ===================
__global__ __launch_bounds__(256) void k_attn(
    const u16* __restrict__ qh, const u16* __restrict__ kT, const u16* __restrict__ vbuf,
    float* __restrict__ att)
{
  __shared__ __align__(16) u16 KL[8192];       // K^T [1024 keys][8 d]
  __shared__ __align__(16) u16 VL[8*1032];     // V [8 dv][1024+8 keys]
  int qt = blockIdx.x;
  int bh = blockIdx.y;
  int b = bh >> 3, h = bh & 7;
  int tid = threadIdx.x, lane = tid & 63, wv = tid >> 6, quad = lane >> 4, c15 = lane & 15;
  {
    const uint4* kg = (const uint4*)(kT + ((size_t)bh << 13));
    uint4* kl = (uint4*)KL;
    for (int i = tid; i < 1024; i += 256) kl[i] = kg[i];
    const u16* vg = vbuf + (size_t)(b*64 + h*8)*1024;
    for (int i = tid; i < 1024; i += 256) {
      int dv = i >> 7, k8 = (i & 127) << 3;
      *(uint4*)(VL + dv*1032 + k8) = *(const uint4*)(vg + dv*1024 + k8);
    }
  }
  __syncthreads();
  int qg = qt*64 + wv*16 + c15;
  int qv = qg < 4224 ? qg : 4224;
  h4 bq = {(_Float16)0.f,(_Float16)0.f,(_Float16)0.f,(_Float16)0.f};
  const u16* qp = qh + (size_t)(b*64 + h*8)*4225;
  if (quad < 2) {
    #pragma unroll
    for (int j=0;j<4;j++) bq[j] = u2h(qp[(quad*4+j)*4225 + qv]);
  }
  const f4 zf = {0.f,0.f,0.f,0.f};
  // pass 1: max over keys (per q column = lane&15)
  float mr = -3.0e38f;
  for (int kt=0; kt<64; ++kt) {
    h4 ak = {(_Float16)0.f,(_Float16)0.f,(_Float16)0.f,(_Float16)0.f};
    if (quad < 2) ak = *(const h4*)(KL + (kt*16 + c15)*8 + quad*4);
    f4 s = __builtin_amdgcn_mfma_f32_16x16x16f16(ak, bq, zf, 0, 0, 0);
    mr = fmaxf(mr, fmaxf(fmaxf(s[0], s[1]), fmaxf(s[2], s[3])));
  }
  mr = fmaxf(mr, __shfl_xor(mr, 16, 64));
  mr = fmaxf(mr, __shfl_xor(mr, 32, 64));
  // pass 2: exp2 + PV (P^T in C-layout == B-operand layout -> no transpose needed)
  float l = 0.f;
  f4 O = {0.f,0.f,0.f,0.f};
  for (int kt=0; kt<64; ++kt) {
    h4 ak = {(_Float16)0.f,(_Float16)0.f,(_Float16)0.f,(_Float16)0.f};
    if (quad < 2) ak = *(const h4*)(KL + (kt*16 + c15)*8 + quad*4);
    f4 s = __builtin_amdgcn_mfma_f32_16x16x16f16(ak, bq, zf, 0, 0, 0);
    float p0 = exp2f(s[0]-mr), p1 = exp2f(s[1]-mr), p2 = exp2f(s[2]-mr), p3 = exp2f(s[3]-mr);
    l += (p0+p1)+(p2+p3);
    h4 pf; pf[0]=(_Float16)p0; pf[1]=(_Float16)p1; pf[2]=(_Float16)p2; pf[3]=(_Float16)p3;
    h4 av = {(_Float16)0.f,(_Float16)0.f,(_Float16)0.f,(_Float16)0.f};
    if (c15 < 8) av = *(const h4*)(VL + c15*1032 + kt*16 + quad*4);
    O = __builtin_amdgcn_mfma_f32_16x16x16f16(av, pf, O, 0, 0, 0);
  }
  l += __shfl_xor(l, 16, 64);
  l += __shfl_xor(l, 32, 64);
  float rinv = __builtin_amdgcn_rcpf(l);
  if (qg < 4225 && quad < 2) {
    #pragma unroll
    for (int rg=0; rg<4; rg++)
      att[(size_t)(b*64 + h*8 + quad*4 + rg)*4225 + qg] = O[rg]*rinv;
  }
}

// =================== K4: output projection + shortcut add ===================
__global__ __launch_bounds__(256) void k_proj(
    const float* __restrict__ att, const float* __restrict__ woT, float* __restrict__ outF)
{
  int pt = blockIdx.x;
  int cb = blockIdx.y * 32;
  int b = blockIdx.z;
  int pix = pt*256 + threadIdx.x;
  bool okp = pix < 4225;
  int pc = okp ? pix : 0;
  float acc[32];
  #pragma unroll
  for (int i=0;i<32;i++) acc[i]=0.f;
  const float* ap = att + (size_t)b*64*4225 + pc;
  for (int d=0; d<64; ++d) {
    float a = ap[(size_t)d*4225];
    const float* wr = woT + d*128 + cb;      // uniform -> scalar loads
    #pragma unroll
    for (int cc=0; cc<32; cc++) acc[cc] += wr[cc]*a;
  }
  if (okp) {
    float* op = outF + (size_t)(b*128 + cb)*4225 + pix;
    #pragma unroll
    for (int cc=0; cc<32; cc++) op[(size_t)cc*4225] += acc[cc];
  }
}

extern "C" void kernel_launch(void* const* d_in, const int* in_sizes, int n_in,
                              void* d_out, int out_size, void* d_ws, size_t ws_size,
                              hipStream_t stream) {
  const float* x     = (const float*)d_in[0];
  const float* gamma = (const float*)d_in[1];
  const float* beta  = (const float*)d_in[2];
  const float* mean  = (const float*)d_in[3];
  const float* var   = (const float*)d_in[4];
  const float* w_sc  = (const float*)d_in[5];
  const float* w_q   = (const float*)d_in[6];
  const float* w_k   = (const float*)d_in[7];
  const float* w_v   = (const float*)d_in[8];
  const float* w_o   = (const float*)d_in[9];
  char* ws = (char*)d_ws;
  u16*   xr   = (u16*)(ws + O_XR);
  u16*   wpt  = (u16*)(ws + O_WPT);
  u16*   qhb  = (u16*)(ws + O_QH);
  u16*   kT   = (u16*)(ws + O_KT);
  u16*   vbuf = (u16*)(ws + O_V);
  float* att  = (float*)(ws + O_ATT);
  float* wkT  = (float*)(ws + O_WKT);
  float* wvT  = (float*)(ws + O_WVT);
  float* woT  = (float*)(ws + O_WOT);
  float* outF = (float*)d_out;

  k_prep<<<2912, 256, 0, stream>>>(x, gamma, beta, mean, var, w_sc, w_q, w_k, w_v, w_o,
                                   xr, wpt, wkT, wvT, woT);
  k_conv_kv<<<1051, 256, 0, stream>>>(xr, wpt, wkT, wvT, outF, qhb, kT, vbuf);
  k_attn<<<dim3(67, 32), 256, 0, stream>>>(qhb, kT, vbuf, att);
  k_proj<<<dim3(17, 4, 4), 256, 0, stream>>>(att, woT, outF);
}

// Round 3
// 156.765 us; speedup vs baseline: 1.2442x; 1.2442x over previous
//
#include <hip/hip_runtime.h>

typedef unsigned short u16;
typedef unsigned int u32;

typedef float f4 __attribute__((ext_vector_type(4)));
typedef short s8v __attribute__((ext_vector_type(8)));
typedef u16 us8 __attribute__((ext_vector_type(8)));
typedef _Float16 h4 __attribute__((ext_vector_type(4)));
typedef __fp16 g2 __attribute__((ext_vector_type(2)));

__device__ __forceinline__ u16 f2bf(float x){ u32 b=__float_as_uint(x); b += 0x7FFFu + ((b>>16)&1u); return (u16)(b>>16); }
__device__ __forceinline__ u16 f2h(float x){ union{_Float16 h; u16 u;} c; c.h=(_Float16)x; return c.u; }
__device__ __forceinline__ _Float16 u2h(u16 u){ union{u16 u; _Float16 h;} c; c.u=u; return c.h; }

// ---- workspace byte offsets ----
#define O_XR   4096u                     // bf16 xr  [4][256][1024]
#define O_XRT  (O_XR  + 2097152u)        // bf16 xrT [4][1024][256]
#define O_WPT  (O_XRT + 2097152u)        // bf16 conv A, 4 parity classes [192][Kp]
#define O_QH   (O_WPT + 884736u)         // f16  q (pre-scaled) [4][64][4225]
#define O_KT   (O_QH  + 2163200u)        // f16  k [b][h][1024 key][8 d]
#define O_V    (O_KT  + 524288u)         // f16  v [b][64 dv][1024 key]
#define O_ATT  (O_V   + 524288u)         // bf16 attT [4][4225][64 dv]
#define O_WKV  (O_ATT + 2163200u)        // bf16 [128][256]  (w_k rows 0-63, w_v rows 64-127)
#define O_WO2  (O_WKV + 65536u)          // bf16 [128][64]   (w_o direct cast)

// =================== K1: BN+ReLU (+transpose) + weight re-layouts ===================
__global__ __launch_bounds__(256) void k_prep(
    const float* __restrict__ x, const float* __restrict__ gamma, const float* __restrict__ beta,
    const float* __restrict__ mean, const float* __restrict__ var,
    const float* __restrict__ w_sc, const float* __restrict__ w_q,
    const float* __restrict__ w_k, const float* __restrict__ w_v, const float* __restrict__ w_o,
    u16* __restrict__ xr, u16* __restrict__ xrT, u16* __restrict__ wpt,
    u16* __restrict__ wkv, u16* __restrict__ wo2)
{
  int bi = blockIdx.x, tid = threadIdx.x;
  if (bi < 256) {                       // BN+ReLU, write xr [c][pix] and xrT [pix][c]
    int b = bi >> 6, ct = (bi >> 4) & 3, pt = bi & 15;
    int r = tid >> 2, g = tid & 3;
    int c = ct*64 + r;
    float s = gamma[c] * rsqrtf(var[c] + 1e-5f);
    float sh = beta[c] - mean[c]*s;
    int pixb = pt*64 + g*16;
    const f4* xp = (const f4*)(x + (((size_t)((b<<8)+c))<<10) + pixb);
    u16 t[16];
    #pragma unroll
    for (int i=0;i<4;i++){
      f4 v = xp[i];
      t[i*4+0]=f2bf(fmaxf(v[0]*s+sh,0.f));
      t[i*4+1]=f2bf(fmaxf(v[1]*s+sh,0.f));
      t[i*4+2]=f2bf(fmaxf(v[2]*s+sh,0.f));
      t[i*4+3]=f2bf(fmaxf(v[3]*s+sh,0.f));
    }
    us8* xo = (us8*)(xr + (((size_t)((b<<8)+c))<<10) + pixb);
    xo[0] = *(us8*)t; xo[1] = *(us8*)(t+8);
    u16* xt = xrT + (((size_t)((b<<10)+pixb))<<8) + c;
    #pragma unroll
    for (int i=0;i<16;i++) xt[(size_t)i<<8] = t[i];
    return;
  }
  int wid = (bi - 256)*256 + tid;
  if (wid < 442368) {
    // jax conv_transpose (no flip): ky=0 -> (py=0,dy=1); ky=1 -> (py=1,dy=0); ky=2 -> (py=0,dy=0)
    int c, m, ky, kx; float val;
    if (wid < 294912) {
      c = wid / 1152; int r = wid - c*1152; m = r / 9; int t9 = r - m*9; ky = t9/3; kx = t9 - ky*3;
      val = w_sc[wid];
    } else {
      int i2 = wid - 294912;
      c = i2 / 576; int r = i2 - c*576; m = r / 9; int t9 = r - m*9; ky = t9/3; kx = t9 - ky*3;
      val = w_q[i2] * 0.51007023f;   // log2(e)/sqrt(8) folded into q weights
      m += 128;
    }
    int py = (ky==1) ? 1 : 0; int dy = (ky==0) ? 1 : 0;
    int px = (kx==1) ? 1 : 0; int dx = (kx==0) ? 1 : 0;
    int cls = py*2 + px;
    int tt, KP, base;
    if (cls==0){ tt = dy*2+dx; KP=1024; base=0; }
    else if (cls==1){ tt = dy; KP=512; base=196608; }
    else if (cls==2){ tt = dx; KP=512; base=294912; }
    else { tt = 0; KP=256; base=393216; }
    wpt[base + m*KP + tt*256 + c] = f2bf(val);
  } else if (wid < 475136) {
    int i = wid - 442368; int m = i >> 8, c = i & 255;
    float vv = (m < 64) ? w_k[m*256 + c] : w_v[(m-64)*256 + c];
    wkv[m*256 + c] = f2bf(vv);
  } else if (wid < 483328) {
    int i = wid - 475136;
    wo2[i] = f2bf(w_o[i]);
  }
}

// =================== K2: conv-transpose GEMM + k/v GEMM (MFMA) ===================
template<int PY,int PX,int TT>
__device__ __forceinline__ void conv_cls(
    const u16* __restrict__ xrT, const u16* __restrict__ wcls,
    float* __restrict__ outF, u16* __restrict__ qh,
    int mb, int nb, u16* Blds)
{
  constexpr int Hy = 33 - PY, Wx = 33 - PX;
  constexpr int NC = 4*Hy*Wx;
  constexpr int KP = TT*256;
  constexpr int NKT = KP/32;
  int tid = threadIdx.x;
  int lane = tid & 63, wv = tid >> 6, quad = lane >> 4, c15 = lane & 15;
  int sn = tid >> 2, sg = tid & 3;
  int n_g = nb*64 + sn;
  bool nv = n_g < NC;
  int bb=0, yq=0, xq=0;
  if (nv) { bb = n_g/(Hy*Wx); int rem = n_g - bb*(Hy*Wx); yq = rem/Wx; xq = rem - yq*Wx; }
  f4 acc[4];
  #pragma unroll
  for (int i=0;i<4;i++) acc[i] = (f4){0.f,0.f,0.f,0.f};
  const u16* arow = wcls + (size_t)(mb*64 + wv*16 + c15)*KP + quad*8;
  for (int kt = 0; kt < NKT; ++kt) {
    int tt = kt >> 3;
    int cb = (kt & 7) * 32;
    int dy, dx;
    if (TT==4){ dy = tt>>1; dx = tt&1; }
    else if (TT==2){ if (PX==1){ dy=tt; dx=0; } else { dy=0; dx=tt; } }
    else { dy=0; dx=0; }
    int ii = yq - dy, jj = xq - dx;
    bool ok = nv && (ii>=0) && (ii<32) && (jj>=0) && (jj<32);
    us8 vals = (us8)0;
    if (ok) vals = *(const us8*)(xrT + (((size_t)((bb<<10) + ii*32 + jj))<<8) + cb + sg*8);
    __syncthreads();
    *(us8*)(Blds + sn*40 + sg*8) = vals;       // B-LDS [n][k], stride 40
    __syncthreads();
    s8v a = *(const s8v*)(arow + kt*32);       // A direct from global (L2-resident)
    #pragma unroll
    for (int t4=0;t4<4;t4++) {
      s8v bf = *(const s8v*)(Blds + (t4*16 + c15)*40 + quad*8);
      acc[t4] = __builtin_amdgcn_mfma_f32_16x16x32_bf16(a, bf, acc[t4], 0, 0, 0);
    }
  }
  int mrow = mb*64 + wv*16 + quad*4;
  #pragma unroll
  for (int t4=0;t4<4;t4++) {
    int n2 = nb*64 + t4*16 + c15;
    if (n2 < NC) {
      int bb2 = n2/(Hy*Wx); int rem = n2 - bb2*(Hy*Wx); int yq2 = rem/Wx; int xq2 = rem - yq2*Wx;
      int pix = (2*yq2 + PY)*65 + (2*xq2 + PX);
      #pragma unroll
      for (int rg=0; rg<4; rg++) {
        int m = mrow + rg;
        float vvv = acc[t4][rg];
        if (m < 128) outF[(size_t)(bb2*128 + m)*4225 + pix] = vvv;
        else qh[(size_t)(bb2*64 + (m-128))*4225 + pix] = f2h(vvv);
      }
    }
  }
}

__global__ __launch_bounds__(256) void k_conv(
    const u16* __restrict__ xrT, const u16* __restrict__ wpt, const u16* __restrict__ wkv,
    float* __restrict__ outF, u16* __restrict__ qh,
    u16* __restrict__ kT, u16* __restrict__ vbuf)
{
  __shared__ __align__(16) u16 Blds[64*40];
  int bi = blockIdx.x;
  if (bi < 795) {
    int mb = bi % 3, cy = bi / 3;
    if (cy < 69)       conv_cls<0,0,4>(xrT, wpt,          outF, qh, mb, cy,     Blds);
    else if (cy < 135) conv_cls<0,1,2>(xrT, wpt + 196608, outF, qh, mb, cy-69,  Blds);
    else if (cy < 201) conv_cls<1,0,2>(xrT, wpt + 294912, outF, qh, mb, cy-135, Blds);
    else               conv_cls<1,1,1>(xrT, wpt + 393216, outF, qh, mb, cy-201, Blds);
    return;
  }
  // k/v GEMM: [128 m] x [256 c] x [4096 n]
  int t = bi - 795;
  int mb = t & 1, nb = t >> 1;
  int tid = threadIdx.x;
  int lane = tid & 63, wv = tid >> 6, quad = lane >> 4, c15 = lane & 15;
  int sn = tid >> 2, sg = tid & 3;
  int n_g = nb*64 + sn;                 // 0..4095
  f4 acc[4];
  #pragma unroll
  for (int i=0;i<4;i++) acc[i] = (f4){0.f,0.f,0.f,0.f};
  const u16* arow = wkv + (size_t)(mb*64 + wv*16 + c15)*256 + quad*8;
  for (int kt = 0; kt < 8; ++kt) {
    us8 vals = *(const us8*)(xrT + (((size_t)n_g)<<8) + kt*32 + sg*8);
    __syncthreads();
    *(us8*)(Blds + sn*40 + sg*8) = vals;
    __syncthreads();
    s8v a = *(const s8v*)(arow + kt*32);
    #pragma unroll
    for (int t4=0;t4<4;t4++) {
      s8v bf = *(const s8v*)(Blds + (t4*16 + c15)*40 + quad*8);
      acc[t4] = __builtin_amdgcn_mfma_f32_16x16x32_bf16(a, bf, acc[t4], 0, 0, 0);
    }
  }
  int ml = wv*16 + quad*4;              // 0..60, within this mb half
  #pragma unroll
  for (int t4=0;t4<4;t4++) {
    int n2 = nb*64 + t4*16 + c15;
    int b = n2 >> 10, pix = n2 & 1023;
    if (mb == 0) {                      // k rows: store kT [b][h][key][d] packed f16x4
      int h = ml >> 3, d0 = ml & 7;
      u16 pk[4];
      #pragma unroll
      for (int rg=0; rg<4; rg++) pk[rg] = f2h(acc[t4][rg]);
      *(uint2*)(kT + ((size_t)(b*8+h)<<13) + pix*8 + d0) = *(uint2*)pk;
    } else {                            // v rows: vbuf [b][dv][key]
      #pragma unroll
      for (int rg=0; rg<4; rg++)
        vbuf[(((size_t)(b*64 + ml + rg))<<10) + pix] = f2h(acc[t4][rg]);
    }
  }
}

// =================== K3: attention ===================
// KL [1024 key][16]: d 0-7 = k, d 8 = 1.0 (max-fold column), d 9-15 = 0
// VL [9 dv][1032]:   dv 0-7 = v, dv 8 = 1.0 (l-sum row)
__global__ __launch_bounds__(256) void k_attn(
    const u16* __restrict__ qh, const u16* __restrict__ kT, const u16* __restrict__ vbuf,
    u16* __restrict__ attT)
{
  __shared__ __align__(16) u16 KL[16384];
  __shared__ __align__(16) u16 VL[9288];
  int qt = blockIdx.x, bh = blockIdx.y;
  int b = bh >> 3, h = bh & 7;
  int tid = threadIdx.x, lane = tid & 63, wv = tid >> 6, quad = lane >> 4, c15 = lane & 15;
  {
    const uint4* kg = (const uint4*)(kT + ((size_t)bh << 13));
    const uint4 onesv = make_uint4(0x00003C00u, 0u, 0u, 0u);
    for (int i = tid; i < 2048; i += 256)
      ((uint4*)KL)[i] = (i & 1) ? onesv : kg[i >> 1];
    const u16* vg = vbuf + ((size_t)(b*64 + h*8) << 10);
    for (int i = tid; i < 1024; i += 256) {
      int dv = i >> 7, k8 = (i & 127) << 3;
      *(uint4*)(VL + dv*1032 + k8) = *(const uint4*)(vg + (dv<<10) + k8);
    }
    if (tid < 129) {
      us8 ones;
      #pragma unroll
      for (int i=0;i<8;i++) ones[i] = 0x3C00;
      *(us8*)(VL + 8*1032 + tid*8) = ones;
    }
  }
  __syncthreads();
  int q0 = qt*128 + wv*32 + c15;
  int q1 = q0 + 16;
  int qa = q0 < 4224 ? q0 : 4224;
  int qb = q1 < 4224 ? q1 : 4224;
  h4 bq0 = (h4)(_Float16)0.f, bq1 = (h4)(_Float16)0.f;
  const u16* qp = qh + (size_t)(b*64 + h*8)*4225;
  if (quad < 2) {
    #pragma unroll
    for (int j=0;j<4;j++) { bq0[j] = u2h(qp[(quad*4+j)*4225 + qa]); bq1[j] = u2h(qp[(quad*4+j)*4225 + qb]); }
  }
  const u16* klb = KL + c15*16 + quad*4;
  int vr = c15 > 8 ? 8 : c15;
  const u16* vlb = VL + vr*1032 + quad*4;
  const f4 zf = {0.f,0.f,0.f,0.f};
  // pass 1: per-column max
  float m0 = -3.0e38f, m1 = -3.0e38f;
  #pragma unroll 16
  for (int kt=0; kt<64; ++kt) {
    h4 ak = *(const h4*)(klb + kt*256);
    f4 s0 = __builtin_amdgcn_mfma_f32_16x16x16f16(ak, bq0, zf, 0, 0, 0);
    f4 s1 = __builtin_amdgcn_mfma_f32_16x16x16f16(ak, bq1, zf, 0, 0, 0);
    m0 = fmaxf(m0, fmaxf(fmaxf(s0[0],s0[1]), fmaxf(s0[2],s0[3])));
    m1 = fmaxf(m1, fmaxf(fmaxf(s1[0],s1[1]), fmaxf(s1[2],s1[3])));
  }
  m0 = fmaxf(m0, __shfl_xor(m0, 16, 64)); m0 = fmaxf(m0, __shfl_xor(m0, 32, 64));
  m1 = fmaxf(m1, __shfl_xor(m1, 16, 64)); m1 = fmaxf(m1, __shfl_xor(m1, 32, 64));
  // fold -max into the d=8 ones-column of K via q fragment (quad 2, reg 0)
  if (quad == 2) { bq0[0] = (_Float16)(-m0); bq1[0] = (_Float16)(-m1); }
  // pass 2: exp2 + PV (P^T C-layout == B-operand layout)
  f4 O0 = {0.f,0.f,0.f,0.f}, O1 = {0.f,0.f,0.f,0.f};
  #pragma unroll 8
  for (int kt=0; kt<64; ++kt) {
    h4 ak = *(const h4*)(klb + kt*256);
    f4 s0 = __builtin_amdgcn_mfma_f32_16x16x16f16(ak, bq0, zf, 0, 0, 0);
    f4 s1 = __builtin_amdgcn_mfma_f32_16x16x16f16(ak, bq1, zf, 0, 0, 0);
    g2 p0l = __builtin_amdgcn_cvt_pkrtz(__builtin_amdgcn_exp2f(s0[0]), __builtin_amdgcn_exp2f(s0[1]));
    g2 p0h = __builtin_amdgcn_cvt_pkrtz(__builtin_amdgcn_exp2f(s0[2]), __builtin_amdgcn_exp2f(s0[3]));
    g2 p1l = __builtin_amdgcn_cvt_pkrtz(__builtin_amdgcn_exp2f(s1[0]), __builtin_amdgcn_exp2f(s1[1]));
    g2 p1h = __builtin_amdgcn_cvt_pkrtz(__builtin_amdgcn_exp2f(s1[2]), __builtin_amdgcn_exp2f(s1[3]));
    h4 pf0; pf0[0]=(_Float16)p0l[0]; pf0[1]=(_Float16)p0l[1]; pf0[2]=(_Float16)p0h[0]; pf0[3]=(_Float16)p0h[1];
    h4 pf1; pf1[0]=(_Float16)p1l[0]; pf1[1]=(_Float16)p1l[1]; pf1[2]=(_Float16)p1h[0]; pf1[3]=(_Float16)p1h[1];
    h4 av = *(const h4*)(vlb + kt*16);
    O0 = __builtin_amdgcn_mfma_f32_16x16x16f16(av, pf0, O0, 0, 0, 0);
    O1 = __builtin_amdgcn_mfma_f32_16x16x16f16(av, pf1, O1, 0, 0, 0);
  }
  float l0 = __shfl(O0[0], 32 + c15, 64);
  float l1 = __shfl(O1[0], 32 + c15, 64);
  float r0 = __builtin_amdgcn_rcpf(l0);
  float r1 = __builtin_amdgcn_rcpf(l1);
  if (quad < 2) {
    if (q0 < 4225) {
      u16 pk[4];
      #pragma unroll
      for (int rg=0;rg<4;rg++) pk[rg] = f2bf(O0[rg]*r0);
      *(uint2*)(attT + ((size_t)(b*4225 + q0)<<6) + h*8 + quad*4) = *(uint2*)pk;
    }
    if (q1 < 4225) {
      u16 pk[4];
      #pragma unroll
      for (int rg=0;rg<4;rg++) pk[rg] = f2bf(O1[rg]*r1);
      *(uint2*)(attT + ((size_t)(b*4225 + q1)<<6) + h*8 + quad*4) = *(uint2*)pk;
    }
  }
}

// =================== K4: output projection GEMM + shortcut add ===================
__global__ __launch_bounds__(256) void k_proj(
    const u16* __restrict__ attT, const u16* __restrict__ wo2, float* __restrict__ outF)
{
  __shared__ __align__(16) u16 Blds[64*40];
  int nbi = blockIdx.x, mb = blockIdx.y, b = blockIdx.z;
  int tid = threadIdx.x;
  int lane = tid & 63, wv = tid >> 6, quad = lane >> 4, c15 = lane & 15;
  int sn = tid >> 2, sg = tid & 3;
  int n_g = nbi*64 + sn;
  int pix = n_g < 4224 ? n_g : 4224;
  f4 acc[4];
  #pragma unroll
  for (int i=0;i<4;i++) acc[i] = (f4){0.f,0.f,0.f,0.f};
  const u16* arow = wo2 + (size_t)(mb*64 + wv*16 + c15)*64 + quad*8;
  #pragma unroll
  for (int kt = 0; kt < 2; ++kt) {
    us8 vals = *(const us8*)(attT + (((size_t)(b*4225 + pix))<<6) + kt*32 + sg*8);
    __syncthreads();
    *(us8*)(Blds + sn*40 + sg*8) = vals;
    __syncthreads();
    s8v a = *(const s8v*)(arow + kt*32);
    #pragma unroll
    for (int t4=0;t4<4;t4++) {
      s8v bf = *(const s8v*)(Blds + (t4*16 + c15)*40 + quad*8);
      acc[t4] = __builtin_amdgcn_mfma_f32_16x16x32_bf16(a, bf, acc[t4], 0, 0, 0);
    }
  }
  int mrow = mb*64 + wv*16 + quad*4;
  #pragma unroll
  for (int t4=0;t4<4;t4++) {
    int n2 = nbi*64 + t4*16 + c15;
    if (n2 < 4225) {
      float* op = outF + (size_t)(b*128 + mrow)*4225 + n2;
      #pragma unroll
      for (int rg=0; rg<4; rg++) op[(size_t)rg*4225] += acc[t4][rg];
    }
  }
}

extern "C" void kernel_launch(void* const* d_in, const int* in_sizes, int n_in,
                              void* d_out, int out_size, void* d_ws, size_t ws_size,
                              hipStream_t stream) {
  const float* x     = (const float*)d_in[0];
  const float* gamma = (const float*)d_in[1];
  const float* beta  = (const float*)d_in[2];
  const float* mean  = (const float*)d_in[3];
  const float* var   = (const float*)d_in[4];
  const float* w_sc  = (const float*)d_in[5];
  const float* w_q   = (const float*)d_in[6];
  const float* w_k   = (const float*)d_in[7];
  const float* w_v   = (const float*)d_in[8];
  const float* w_o   = (const float*)d_in[9];
  char* ws = (char*)d_ws;
  u16*   xr   = (u16*)(ws + O_XR);
  u16*   xrT  = (u16*)(ws + O_XRT);
  u16*   wpt  = (u16*)(ws + O_WPT);
  u16*   qhb  = (u16*)(ws + O_QH);
  u16*   kT   = (u16*)(ws + O_KT);
  u16*   vbuf = (u16*)(ws + O_V);
  u16*   attT = (u16*)(ws + O_ATT);
  u16*   wkv  = (u16*)(ws + O_WKV);
  u16*   wo2  = (u16*)(ws + O_WO2);
  float* outF = (float*)d_out;

  k_prep<<<2144, 256, 0, stream>>>(x, gamma, beta, mean, var, w_sc, w_q, w_k, w_v, w_o,
                                   xr, xrT, wpt, wkv, wo2);
  k_conv<<<923, 256, 0, stream>>>(xrT, wpt, wkv, outF, qhb, kT, vbuf);
  k_attn<<<dim3(34, 32), 256, 0, stream>>>(qhb, kT, vbuf, attT);
  k_proj<<<dim3(67, 2, 4), 256, 0, stream>>>(attT, wo2, outF);
}

// Round 4
// 136.047 us; speedup vs baseline: 1.4337x; 1.1523x over previous
//
#include <hip/hip_runtime.h>

typedef unsigned short u16;
typedef unsigned int u32;

typedef float f4 __attribute__((ext_vector_type(4)));
typedef short s8v __attribute__((ext_vector_type(8)));
typedef u16 us8 __attribute__((ext_vector_type(8)));
typedef _Float16 h4 __attribute__((ext_vector_type(4)));
typedef __fp16 g2 __attribute__((ext_vector_type(2)));

__device__ __forceinline__ u16 f2bf(float x){ u32 b=__float_as_uint(x); b += 0x7FFFu + ((b>>16)&1u); return (u16)(b>>16); }
__device__ __forceinline__ u16 f2h(float x){ union{_Float16 h; u16 u;} c; c.h=(_Float16)x; return c.u; }

// ---- workspace byte offsets (xr slot retired, offsets kept stable) ----
#define O_XRT  2101248u                  // bf16 xrT [4][1024 pix][256 c]
#define O_WPT  (O_XRT + 2097152u)        // bf16 conv A, 4 parity classes [192][Kp]
#define O_QH   (O_WPT + 884736u)         // f16  q (pre-scaled) [4][4225 pix][64 d]
#define O_KT   (O_QH  + 2163200u)        // f16  k [b][h][1024 key][8 d]
#define O_V    (O_KT  + 524288u)         // f16  v [b][64 dv][1024 key]
#define O_ATT  (O_V   + 524288u)         // bf16 attT [4][4225][64 dv]
#define O_WKV  (O_ATT + 2163200u)        // bf16 [128][256]  (w_k rows 0-63, w_v rows 64-127)
#define O_WO2  (O_WKV + 65536u)          // bf16 [128][64]   (w_o direct cast)

// =================== K1: BN+ReLU transpose + weight re-layouts ===================
__global__ __launch_bounds__(256) void k_prep(
    const float* __restrict__ x, const float* __restrict__ gamma, const float* __restrict__ beta,
    const float* __restrict__ mean, const float* __restrict__ var,
    const float* __restrict__ w_sc, const float* __restrict__ w_q,
    const float* __restrict__ w_k, const float* __restrict__ w_v, const float* __restrict__ w_o,
    u16* __restrict__ xrT, u16* __restrict__ wpt,
    u16* __restrict__ wkv, u16* __restrict__ wo2)
{
  __shared__ float SS[128], SH[128];
  __shared__ __align__(16) u16 T[32*136];      // 32 pix rows, stride 136 u16 (16B-aligned rows)
  int bi = blockIdx.x, tid = threadIdx.x;
  if (bi < 256) {                       // BN+ReLU -> xrT [pix][c], tile = 32 pix x 128 c
    int b = bi >> 6, pt = (bi >> 1) & 31, ch = bi & 1;
    int pix0 = pt*32, c0 = ch*128;
    if (tid < 128) {
      int c = c0 + tid;
      float s = gamma[c]*rsqrtf(var[c] + 1e-5f);
      SS[tid] = s; SH[tid] = beta[c] - mean[c]*s;
    }
    __syncthreads();
    int pix_l = tid & 31, c_l = tid >> 5;
    #pragma unroll 4
    for (int it = 0; it < 16; ++it) {
      int cl = it*8 + c_l;
      float v = x[(((size_t)(b*256 + c0 + cl))<<10) + pix0 + pix_l];
      T[pix_l*136 + cl] = f2bf(fmaxf(v*SS[cl] + SH[cl], 0.f));
    }
    __syncthreads();
    int pix_r = tid >> 3, j = tid & 7;
    us8 v0 = *(const us8*)(T + pix_r*136 + j*8);
    us8 v1 = *(const us8*)(T + pix_r*136 + 64 + j*8);
    u16* dst = xrT + (((size_t)(b*1024 + pix0 + pix_r))<<8) + c0;
    *(us8*)(dst + j*8) = v0;
    *(us8*)(dst + 64 + j*8) = v1;
    return;
  }
  int wid = (bi - 256)*256 + tid;
  if (wid < 442368) {
    // jax conv_transpose (no flip): ky=0 -> (py=0,dy=1); ky=1 -> (py=1,dy=0); ky=2 -> (py=0,dy=0)
    int c, m, ky, kx; float val;
    if (wid < 294912) {
      c = wid / 1152; int r = wid - c*1152; m = r / 9; int t9 = r - m*9; ky = t9/3; kx = t9 - ky*3;
      val = w_sc[wid];
    } else {
      int i2 = wid - 294912;
      c = i2 / 576; int r = i2 - c*576; m = r / 9; int t9 = r - m*9; ky = t9/3; kx = t9 - ky*3;
      val = w_q[i2] * 0.51007023f;   // log2(e)/sqrt(8) folded into q weights
      m += 128;
    }
    int py = (ky==1) ? 1 : 0; int dy = (ky==0) ? 1 : 0;
    int px = (kx==1) ? 1 : 0; int dx = (kx==0) ? 1 : 0;
    int cls = py*2 + px;
    int tt, KP, base;
    if (cls==0){ tt = dy*2+dx; KP=1024; base=0; }
    else if (cls==1){ tt = dy; KP=512; base=196608; }
    else if (cls==2){ tt = dx; KP=512; base=294912; }
    else { tt = 0; KP=256; base=393216; }
    wpt[base + m*KP + tt*256 + c] = f2bf(val);
  } else if (wid < 475136) {
    int i = wid - 442368; int m = i >> 8, c = i & 255;
    float vv = (m < 64) ? w_k[m*256 + c] : w_v[(m-64)*256 + c];
    wkv[m*256 + c] = f2bf(vv);
  } else if (wid < 483328) {
    int i = wid - 475136;
    wo2[i] = f2bf(w_o[i]);
  }
}

// =================== K2: conv-transpose GEMM + k/v GEMM (MFMA) ===================
template<int PY,int PX,int TT>
__device__ __forceinline__ void conv_cls(
    const u16* __restrict__ xrT, const u16* __restrict__ wcls,
    float* __restrict__ outF, u16* __restrict__ qh,
    int mb, int nb, u16* Blds)
{
  constexpr int Hy = 33 - PY, Wx = 33 - PX;
  constexpr int NC = 4*Hy*Wx;
  constexpr int KP = TT*256;
  constexpr int NKT = KP/32;
  int tid = threadIdx.x;
  int lane = tid & 63, wv = tid >> 6, quad = lane >> 4, c15 = lane & 15;
  int sn = tid >> 2, sg = tid & 3;
  int n_g = nb*64 + sn;
  bool nv = n_g < NC;
  int bb=0, yq=0, xq=0;
  if (nv) { bb = n_g/(Hy*Wx); int rem = n_g - bb*(Hy*Wx); yq = rem/Wx; xq = rem - yq*Wx; }
  f4 acc[4];
  #pragma unroll
  for (int i=0;i<4;i++) acc[i] = (f4){0.f,0.f,0.f,0.f};
  const u16* arow = wcls + (size_t)(mb*64 + wv*16 + c15)*KP + quad*8;
  auto loadB = [&](int kt)->us8 {
    int tt = kt >> 3, cb = (kt & 7)*32;
    int dy, dx;
    if (TT==4){ dy = tt>>1; dx = tt&1; }
    else if (TT==2){ if (PX==1){ dy=tt; dx=0; } else { dy=0; dx=tt; } }
    else { dy=0; dx=0; }
    int ii = yq - dy, jj = xq - dx;
    bool ok = nv && (ii>=0) && (ii<32) && (jj>=0) && (jj<32);
    us8 v = (us8)0;
    if (ok) v = *(const us8*)(xrT + (((size_t)((bb<<10) + ii*32 + jj))<<8) + cb + sg*8);
    return v;
  };
  us8 cur = loadB(0);
  for (int kt = 0; kt < NKT; ++kt) {
    __syncthreads();
    *(us8*)(Blds + sn*40 + sg*8) = cur;
    __syncthreads();
    if (kt + 1 < NKT) cur = loadB(kt + 1);   // prefetch across the MFMA phase
    s8v a = *(const s8v*)(arow + kt*32);
    #pragma unroll
    for (int t4=0;t4<4;t4++) {
      s8v bf = *(const s8v*)(Blds + (t4*16 + c15)*40 + quad*8);
      acc[t4] = __builtin_amdgcn_mfma_f32_16x16x32_bf16(a, bf, acc[t4], 0, 0, 0);
    }
  }
  #pragma unroll
  for (int t4=0;t4<4;t4++) {
    int n2 = nb*64 + t4*16 + c15;
    if (n2 < NC) {
      int bb2 = n2/(Hy*Wx); int rem = n2 - bb2*(Hy*Wx); int yq2 = rem/Wx; int xq2 = rem - yq2*Wx;
      int pix = (2*yq2 + PY)*65 + (2*xq2 + PX);
      if (mb < 2) {                      // shortcut rows -> outF f32
        int mrow = mb*64 + wv*16 + quad*4;
        #pragma unroll
        for (int rg=0; rg<4; rg++)
          outF[(size_t)(bb2*128 + mrow + rg)*4225 + pix] = acc[t4][rg];
      } else {                           // q rows -> qh [b][pix][64] f16, packed
        int dv = wv*16 + quad*4;
        u16 pk[4];
        #pragma unroll
        for (int rg=0; rg<4; rg++) pk[rg] = f2h(acc[t4][rg]);
        *(uint2*)(qh + (((size_t)(bb2*4225 + pix))<<6) + dv) = *(uint2*)pk;
      }
    }
  }
}

__global__ __launch_bounds__(256) void k_conv(
    const u16* __restrict__ xrT, const u16* __restrict__ wpt, const u16* __restrict__ wkv,
    float* __restrict__ outF, u16* __restrict__ qh,
    u16* __restrict__ kT, u16* __restrict__ vbuf)
{
  __shared__ __align__(16) u16 Blds[64*40];
  int bi = blockIdx.x;
  if (bi < 795) {
    int mb = bi % 3, cy = bi / 3;
    if (cy < 69)       conv_cls<0,0,4>(xrT, wpt,          outF, qh, mb, cy,     Blds);
    else if (cy < 135) conv_cls<0,1,2>(xrT, wpt + 196608, outF, qh, mb, cy-69,  Blds);
    else if (cy < 201) conv_cls<1,0,2>(xrT, wpt + 294912, outF, qh, mb, cy-135, Blds);
    else               conv_cls<1,1,1>(xrT, wpt + 393216, outF, qh, mb, cy-201, Blds);
    return;
  }
  // k/v GEMM: [128 m] x [256 c] x [4096 n]
  int t = bi - 795;
  int mb = t & 1, nb = t >> 1;
  int tid = threadIdx.x;
  int lane = tid & 63, wv = tid >> 6, quad = lane >> 4, c15 = lane & 15;
  int sn = tid >> 2, sg = tid & 3;
  int n_g = nb*64 + sn;                 // 0..4095
  f4 acc[4];
  #pragma unroll
  for (int i=0;i<4;i++) acc[i] = (f4){0.f,0.f,0.f,0.f};
  const u16* arow = wkv + (size_t)(mb*64 + wv*16 + c15)*256 + quad*8;
  us8 cur = *(const us8*)(xrT + (((size_t)n_g)<<8) + sg*8);
  for (int kt = 0; kt < 8; ++kt) {
    __syncthreads();
    *(us8*)(Blds + sn*40 + sg*8) = cur;
    __syncthreads();
    if (kt < 7) cur = *(const us8*)(xrT + (((size_t)n_g)<<8) + (kt+1)*32 + sg*8);
    s8v a = *(const s8v*)(arow + kt*32);
    #pragma unroll
    for (int t4=0;t4<4;t4++) {
      s8v bf = *(const s8v*)(Blds + (t4*16 + c15)*40 + quad*8);
      acc[t4] = __builtin_amdgcn_mfma_f32_16x16x32_bf16(a, bf, acc[t4], 0, 0, 0);
    }
  }
  int ml = wv*16 + quad*4;              // 0..60, within this mb half
  #pragma unroll
  for (int t4=0;t4<4;t4++) {
    int n2 = nb*64 + t4*16 + c15;
    int b = n2 >> 10, pix = n2 & 1023;
    if (mb == 0) {                      // k rows: kT [b][h][key][8 d] packed f16x4
      int h = ml >> 3, d0 = ml & 7;
      u16 pk[4];
      #pragma unroll
      for (int rg=0; rg<4; rg++) pk[rg] = f2h(acc[t4][rg]);
      *(uint2*)(kT + ((size_t)(b*8+h)<<13) + pix*8 + d0) = *(uint2*)pk;
    } else {                            // v rows: vbuf [b][dv][key]
      #pragma unroll
      for (int rg=0; rg<4; rg++)
        vbuf[(((size_t)(b*64 + ml + rg))<<10) + pix] = f2h(acc[t4][rg]);
    }
  }
}

// =================== K3: attention (no-max softmax, 1 pass) ===================
// KL [1024 key][8 d] f16 (16KB); VL [9 dv][1032]: dv 0-7 = v, dv 8 = ones (l-sum row)
__global__ __launch_bounds__(256) void k_attn(
    const u16* __restrict__ qh, const u16* __restrict__ kT, const u16* __restrict__ vbuf,
    u16* __restrict__ attT)
{
  __shared__ __align__(16) u16 KL[8192];
  __shared__ __align__(16) u16 VL[9*1032];
  int qt = blockIdx.x, bh = blockIdx.y;
  int b = bh >> 3, h = bh & 7;
  int tid = threadIdx.x, lane = tid & 63, wv = tid >> 6, quad = lane >> 4, c15 = lane & 15;
  {
    const uint4* kg = (const uint4*)(kT + ((size_t)bh << 13));
    for (int i = tid; i < 1024; i += 256) ((uint4*)KL)[i] = kg[i];
    const u16* vg = vbuf + ((size_t)(b*64 + h*8) << 10);
    for (int i = tid; i < 1024; i += 256) {
      int dv = i >> 7, k8 = (i & 127) << 3;
      *(uint4*)(VL + dv*1032 + k8) = *(const uint4*)(vg + (dv<<10) + k8);
    }
    if (tid < 129) {
      us8 ones;
      #pragma unroll
      for (int i=0;i<8;i++) ones[i] = 0x3C00;
      *(us8*)(VL + 8*1032 + tid*8) = ones;
    }
  }
  __syncthreads();
  int q0 = qt*128 + wv*32 + c15;
  int q1 = q0 + 16;
  int qa = q0 < 4224 ? q0 : 4224;
  int qb = q1 < 4224 ? q1 : 4224;
  // q fragment: B[k=d][n=q]; d 8..15 zeroed (kills the unguarded K reads there)
  uint2 t0 = *(const uint2*)(qh + (((size_t)(b*4225 + qa))<<6) + h*8 + (quad&1)*4);
  uint2 t1 = *(const uint2*)(qh + (((size_t)(b*4225 + qb))<<6) + h*8 + (quad&1)*4);
  h4 bq0 = quad < 2 ? *(h4*)&t0 : (h4)(_Float16)0.f;
  h4 bq1 = quad < 2 ? *(h4*)&t1 : (h4)(_Float16)0.f;
  const u16* klb = KL + c15*8 + (quad&1)*4;   // quads 2,3 re-read 0,1 (finite; zeroed by bq)
  int vr = c15 > 8 ? 8 : c15;
  const u16* vlb = VL + vr*1032 + quad*4;
  const f4 zf = {0.f,0.f,0.f,0.f};
  f4 O0 = {0.f,0.f,0.f,0.f}, O1 = {0.f,0.f,0.f,0.f};
  #pragma unroll 8
  for (int kt=0; kt<64; ++kt) {
    h4 ak = *(const h4*)(klb + kt*128);
    h4 av = *(const h4*)(vlb + kt*16);
    f4 s0 = __builtin_amdgcn_mfma_f32_16x16x16f16(ak, bq0, zf, 0, 0, 0);
    f4 s1 = __builtin_amdgcn_mfma_f32_16x16x16f16(ak, bq1, zf, 0, 0, 0);
    g2 p0l = __builtin_amdgcn_cvt_pkrtz(__builtin_amdgcn_exp2f(s0[0]), __builtin_amdgcn_exp2f(s0[1]));
    g2 p0h = __builtin_amdgcn_cvt_pkrtz(__builtin_amdgcn_exp2f(s0[2]), __builtin_amdgcn_exp2f(s0[3]));
    g2 p1l = __builtin_amdgcn_cvt_pkrtz(__builtin_amdgcn_exp2f(s1[0]), __builtin_amdgcn_exp2f(s1[1]));
    g2 p1h = __builtin_amdgcn_cvt_pkrtz(__builtin_amdgcn_exp2f(s1[2]), __builtin_amdgcn_exp2f(s1[3]));
    h4 pf0; pf0[0]=(_Float16)p0l[0]; pf0[1]=(_Float16)p0l[1]; pf0[2]=(_Float16)p0h[0]; pf0[3]=(_Float16)p0h[1];
    h4 pf1; pf1[0]=(_Float16)p1l[0]; pf1[1]=(_Float16)p1l[1]; pf1[2]=(_Float16)p1h[0]; pf1[3]=(_Float16)p1h[1];
    O0 = __builtin_amdgcn_mfma_f32_16x16x16f16(av, pf0, O0, 0, 0, 0);
    O1 = __builtin_amdgcn_mfma_f32_16x16x16f16(av, pf1, O1, 0, 0, 0);
  }
  float l0 = __shfl(O0[0], 32 + c15, 64);   // C row 8 = ones-row dot P = sum p
  float l1 = __shfl(O1[0], 32 + c15, 64);
  float r0 = __builtin_amdgcn_rcpf(l0);
  float r1 = __builtin_amdgcn_rcpf(l1);
  if (quad < 2) {
    if (q0 < 4225) {
      u16 pk[4];
      #pragma unroll
      for (int rg=0;rg<4;rg++) pk[rg] = f2bf(O0[rg]*r0);
      *(uint2*)(attT + (((size_t)(b*4225 + q0))<<6) + h*8 + quad*4) = *(uint2*)pk;
    }
    if (q1 < 4225) {
      u16 pk[4];
      #pragma unroll
      for (int rg=0;rg<4;rg++) pk[rg] = f2bf(O1[rg]*r1);
      *(uint2*)(attT + (((size_t)(b*4225 + q1))<<6) + h*8 + quad*4) = *(uint2*)pk;
    }
  }
}

// =================== K4: output projection GEMM (no LDS) + shortcut add ===================
__global__ __launch_bounds__(256) void k_proj(
    const u16* __restrict__ attT, const u16* __restrict__ wo2, float* __restrict__ outF)
{
  int nbi = blockIdx.x, b = blockIdx.y;
  int tid = threadIdx.x;
  int lane = tid & 63, wv = tid >> 6, quad = lane >> 4, c15 = lane & 15;
  f4 acc[2][4];
  #pragma unroll
  for (int am=0;am<2;am++)
    #pragma unroll
    for (int i=0;i<4;i++) acc[am][i] = (f4){0.f,0.f,0.f,0.f};
  #pragma unroll
  for (int kt = 0; kt < 2; ++kt) {
    s8v a0 = *(const s8v*)(wo2 + (size_t)(wv*32 + c15)*64 + kt*32 + quad*8);
    s8v a1 = *(const s8v*)(wo2 + (size_t)(wv*32 + 16 + c15)*64 + kt*32 + quad*8);
    #pragma unroll
    for (int t4=0;t4<4;t4++) {
      int n = nbi*64 + t4*16 + c15;
      int nc = n < 4224 ? n : 4224;
      s8v bf = *(const s8v*)(attT + (((size_t)(b*4225 + nc))<<6) + kt*32 + quad*8);
      acc[0][t4] = __builtin_amdgcn_mfma_f32_16x16x32_bf16(a0, bf, acc[0][t4], 0, 0, 0);
      acc[1][t4] = __builtin_amdgcn_mfma_f32_16x16x32_bf16(a1, bf, acc[1][t4], 0, 0, 0);
    }
  }
  #pragma unroll
  for (int am=0;am<2;am++) {
    int mrow = wv*32 + am*16 + quad*4;
    #pragma unroll
    for (int t4=0;t4<4;t4++) {
      int n2 = nbi*64 + t4*16 + c15;
      if (n2 < 4225) {
        float* op = outF + (size_t)(b*128 + mrow)*4225 + n2;
        #pragma unroll
        for (int rg=0; rg<4; rg++) op[(size_t)rg*4225] += acc[am][t4][rg];
      }
    }
  }
}

extern "C" void kernel_launch(void* const* d_in, const int* in_sizes, int n_in,
                              void* d_out, int out_size, void* d_ws, size_t ws_size,
                              hipStream_t stream) {
  const float* x     = (const float*)d_in[0];
  const float* gamma = (const float*)d_in[1];
  const float* beta  = (const float*)d_in[2];
  const float* mean  = (const float*)d_in[3];
  const float* var   = (const float*)d_in[4];
  const float* w_sc  = (const float*)d_in[5];
  const float* w_q   = (const float*)d_in[6];
  const float* w_k   = (const float*)d_in[7];
  const float* w_v   = (const float*)d_in[8];
  const float* w_o   = (const float*)d_in[9];
  char* ws = (char*)d_ws;
  u16*   xrT  = (u16*)(ws + O_XRT);
  u16*   wpt  = (u16*)(ws + O_WPT);
  u16*   qhb  = (u16*)(ws + O_QH);
  u16*   kT   = (u16*)(ws + O_KT);
  u16*   vbuf = (u16*)(ws + O_V);
  u16*   attT = (u16*)(ws + O_ATT);
  u16*   wkv  = (u16*)(ws + O_WKV);
  u16*   wo2  = (u16*)(ws + O_WO2);
  float* outF = (float*)d_out;

  k_prep<<<2144, 256, 0, stream>>>(x, gamma, beta, mean, var, w_sc, w_q, w_k, w_v, w_o,
                                   xrT, wpt, wkv, wo2);
  k_conv<<<923, 256, 0, stream>>>(xrT, wpt, wkv, outF, qhb, kT, vbuf);
  k_attn<<<dim3(34, 32), 256, 0, stream>>>(qhb, kT, vbuf, attT);
  k_proj<<<dim3(67, 4), 256, 0, stream>>>(attT, wo2, outF);
}

// Round 5
// 135.531 us; speedup vs baseline: 1.4391x; 1.0038x over previous
//
#include <hip/hip_runtime.h>

typedef unsigned short u16;
typedef unsigned int u32;

typedef float f4 __attribute__((ext_vector_type(4)));
typedef short s8v __attribute__((ext_vector_type(8)));
typedef u16 us8 __attribute__((ext_vector_type(8)));
typedef _Float16 h4 __attribute__((ext_vector_type(4)));
typedef __fp16 g2 __attribute__((ext_vector_type(2)));

__device__ __forceinline__ u16 f2bf(float x){ u32 b=__float_as_uint(x); b += 0x7FFFu + ((b>>16)&1u); return (u16)(b>>16); }
__device__ __forceinline__ u16 f2h(float x){ union{_Float16 h; u16 u;} c; c.h=(_Float16)x; return c.u; }

// ---- workspace byte offsets ----
#define O_XRT  4096u                     // bf16 xrTp [4][34*34 pix][256 c] (zero halo)
#define O_WPT  (O_XRT + 2367488u)        // bf16 conv A, 4 parity classes [192][Kp]
#define O_QH   (O_WPT + 884736u)         // f16  q (pre-scaled) [4][4225 pix][64 d]
#define O_KT   (O_QH  + 2163200u)        // f16  k [b][h][1024 key][8 d]
#define O_V    (O_KT  + 524288u)         // f16  v [b][64 dv][1024 key]
#define O_ATT  (O_V   + 524288u)         // bf16 attT [4][4225][64 dv]
#define O_WKV  (O_ATT + 2163200u)        // bf16 [128][256]  (w_k rows 0-63, w_v rows 64-127)
#define O_WO2  (O_WKV + 65536u)          // bf16 [128][64]   (w_o direct cast)

// =================== K1: BN+ReLU transpose (padded) + weight re-layouts ===================
__global__ __launch_bounds__(256) void k_prep(
    const float* __restrict__ x, const float* __restrict__ gamma, const float* __restrict__ beta,
    const float* __restrict__ mean, const float* __restrict__ var,
    const float* __restrict__ w_sc, const float* __restrict__ w_q,
    const float* __restrict__ w_k, const float* __restrict__ w_v, const float* __restrict__ w_o,
    u16* __restrict__ xrTp, u16* __restrict__ wpt,
    u16* __restrict__ wkv, u16* __restrict__ wo2)
{
  __shared__ float SS[128], SH[128];
  __shared__ __align__(16) u16 T[32*136];
  int bi = blockIdx.x, tid = threadIdx.x;
  if (bi < 256) {                       // BN+ReLU -> xrTp [pad pix][c], tile = 1 image row x 128 c
    int b = bi >> 6, pt = (bi >> 1) & 31, ch = bi & 1;
    int pix0 = pt*32, c0 = ch*128;
    if (tid < 128) {
      int c = c0 + tid;
      float s = gamma[c]*rsqrtf(var[c] + 1e-5f);
      SS[tid] = s; SH[tid] = beta[c] - mean[c]*s;
    }
    __syncthreads();
    int pix_l = tid & 31, c_l = tid >> 5;
    #pragma unroll 4
    for (int it = 0; it < 16; ++it) {
      int cl = it*8 + c_l;
      float v = x[(((size_t)(b*256 + c0 + cl))<<10) + pix0 + pix_l];
      T[pix_l*136 + cl] = f2bf(fmaxf(v*SS[cl] + SH[cl], 0.f));
    }
    __syncthreads();
    int pix_r = tid >> 3, j = tid & 7;
    us8 v0 = *(const us8*)(T + pix_r*136 + j*8);
    us8 v1 = *(const us8*)(T + pix_r*136 + 64 + j*8);
    u16* dst = xrTp + (((size_t)(b*1156 + (pt+1)*34 + 1 + pix_r))<<8) + c0;
    *(us8*)(dst + j*8) = v0;
    *(us8*)(dst + 64 + j*8) = v1;
    return;
  }
  int wid = (bi - 256)*256 + tid;
  if (wid < 442368) {
    // jax conv_transpose (no flip): ky=0 -> (py=0,dy=1); ky=1 -> (py=1,dy=0); ky=2 -> (py=0,dy=0)
    int c, m, ky, kx; float val;
    if (wid < 294912) {
      c = wid / 1152; int r = wid - c*1152; m = r / 9; int t9 = r - m*9; ky = t9/3; kx = t9 - ky*3;
      val = w_sc[wid];
    } else {
      int i2 = wid - 294912;
      c = i2 / 576; int r = i2 - c*576; m = r / 9; int t9 = r - m*9; ky = t9/3; kx = t9 - ky*3;
      val = w_q[i2] * 0.51007023f;   // log2(e)/sqrt(8) folded into q weights
      m += 128;
    }
    int py = (ky==1) ? 1 : 0; int dy = (ky==0) ? 1 : 0;
    int px = (kx==1) ? 1 : 0; int dx = (kx==0) ? 1 : 0;
    int cls = py*2 + px;
    int tt, KP, base;
    if (cls==0){ tt = dy*2+dx; KP=1024; base=0; }
    else if (cls==1){ tt = dy; KP=512; base=196608; }
    else if (cls==2){ tt = dx; KP=512; base=294912; }
    else { tt = 0; KP=256; base=393216; }
    wpt[base + m*KP + tt*256 + c] = f2bf(val);
  } else if (wid < 475136) {
    int i = wid - 442368; int m = i >> 8, c = i & 255;
    float vv = (m < 64) ? w_k[m*256 + c] : w_v[(m-64)*256 + c];
    wkv[m*256 + c] = f2bf(vv);
  } else if (wid < 483328) {
    int i = wid - 475136;
    wo2[i] = f2bf(w_o[i]);
  } else if (wid < 500224) {
    int i = wid - 483328;                // halo zero: 4 b x 132 pix x 32 us8
    int b = i / 4224; int r = i - b*4224;
    int hp = r >> 5, j = r & 31;
    int p;
    if (hp < 34) p = hp;
    else if (hp < 68) p = 33*34 + (hp - 34);
    else if (hp < 100) p = (hp - 68 + 1)*34;
    else p = (hp - 100 + 1)*34 + 33;
    *(us8*)(xrTp + (((size_t)(b*1156 + p))<<8) + j*8) = (us8)0;
  }
}

// =================== K2: conv-transpose GEMM + k/v GEMM (MFMA, dbuf) ===================
template<int PY,int PX,int TT>
__device__ __forceinline__ void conv_cls(
    const u16* __restrict__ xrTp, const u16* __restrict__ wcls,
    float* __restrict__ outF, u16* __restrict__ qh,
    int mb, int nb, u16* Blds)
{
  constexpr int Hy = 33 - PY, Wx = 33 - PX;
  constexpr int NC = 4*Hy*Wx;
  constexpr int KP = TT*256;
  constexpr int NKT = KP/64;
  int tid = threadIdx.x;
  int lane = tid & 63, wv = tid >> 6, quad = lane >> 4, c15 = lane & 15;
  int sn = tid >> 2, sg = tid & 3;
  int n_g = nb*64 + sn;
  int ncl = n_g < NC ? n_g : NC-1;
  int bb = ncl/(Hy*Wx); int rem = ncl - bb*(Hy*Wx); int yq = rem/Wx; int xq = rem - yq*Wx;
  const u16* bsrc = xrTp + (((size_t)(bb*1156 + (yq+1)*34 + xq+1))<<8) + sg*16;
  f4 acc[4];
  #pragma unroll
  for (int i=0;i<4;i++) acc[i] = (f4){0.f,0.f,0.f,0.f};
  const u16* arow = wcls + (size_t)(mb*64 + wv*16 + c15)*KP + quad*8;
  auto loadB = [&](int kt, us8& v0, us8& v1) {
    int tt = kt >> 2, c0 = (kt & 3)*64;
    int dy, dx;
    if (TT==4){ dy = tt>>1; dx = tt&1; }
    else if (TT==2){ if (PX==1){ dy=tt; dx=0; } else { dy=0; dx=tt; } }
    else { dy=0; dx=0; }
    const u16* p = bsrc - (((dy*34+dx))<<8) + c0;
    v0 = *(const us8*)p;
    v1 = *(const us8*)(p+8);
  };
  us8 cv0, cv1; loadB(0, cv0, cv1);
  int pb = 0;
  for (int kt = 0; kt < NKT; ++kt) {
    u16* Bw = Blds + pb*4608;
    *(us8*)(Bw + sn*72 + sg*16) = cv0;
    *(us8*)(Bw + sn*72 + sg*16 + 8) = cv1;
    __syncthreads();
    if (kt + 1 < NKT) loadB(kt+1, cv0, cv1);
    s8v a0 = *(const s8v*)(arow + kt*64);
    s8v a1 = *(const s8v*)(arow + kt*64 + 32);
    #pragma unroll
    for (int t4=0;t4<4;t4++) {
      const u16* br = Blds + pb*4608 + (t4*16 + c15)*72 + quad*8;
      s8v bf0 = *(const s8v*)br;
      s8v bf1 = *(const s8v*)(br + 32);
      acc[t4] = __builtin_amdgcn_mfma_f32_16x16x32_bf16(a0, bf0, acc[t4], 0, 0, 0);
      acc[t4] = __builtin_amdgcn_mfma_f32_16x16x32_bf16(a1, bf1, acc[t4], 0, 0, 0);
    }
    pb ^= 1;
  }
  #pragma unroll
  for (int t4=0;t4<4;t4++) {
    int n2 = nb*64 + t4*16 + c15;
    if (n2 < NC) {
      int bb2 = n2/(Hy*Wx); int rem2 = n2 - bb2*(Hy*Wx); int yq2 = rem2/Wx; int xq2 = rem2 - yq2*Wx;
      int pix = (2*yq2 + PY)*65 + (2*xq2 + PX);
      if (mb < 2) {
        int mrow = mb*64 + wv*16 + quad*4;
        #pragma unroll
        for (int rg=0; rg<4; rg++)
          outF[(size_t)(bb2*128 + mrow + rg)*4225 + pix] = acc[t4][rg];
      } else {
        int dv = wv*16 + quad*4;
        u16 pk[4];
        #pragma unroll
        for (int rg=0; rg<4; rg++) pk[rg] = f2h(acc[t4][rg]);
        *(uint2*)(qh + (((size_t)(bb2*4225 + pix))<<6) + dv) = *(uint2*)pk;
      }
    }
  }
}

__global__ __launch_bounds__(256) void k_conv(
    const u16* __restrict__ xrTp, const u16* __restrict__ wpt, const u16* __restrict__ wkv,
    float* __restrict__ outF, u16* __restrict__ qh,
    u16* __restrict__ kT, u16* __restrict__ vbuf)
{
  __shared__ __align__(16) u16 Blds[2*4608];
  int bi = blockIdx.x;
  if (bi < 795) {
    int mb = bi % 3, cy = bi / 3;
    if (cy < 69)       conv_cls<0,0,4>(xrTp, wpt,          outF, qh, mb, cy,     Blds);
    else if (cy < 135) conv_cls<0,1,2>(xrTp, wpt + 196608, outF, qh, mb, cy-69,  Blds);
    else if (cy < 201) conv_cls<1,0,2>(xrTp, wpt + 294912, outF, qh, mb, cy-135, Blds);
    else               conv_cls<1,1,1>(xrTp, wpt + 393216, outF, qh, mb, cy-201, Blds);
    return;
  }
  // k/v GEMM: [128 m] x [256 c] x [4096 n]
  int t = bi - 795;
  int mb = t & 1, nb = t >> 1;
  int tid = threadIdx.x;
  int lane = tid & 63, wv = tid >> 6, quad = lane >> 4, c15 = lane & 15;
  int sn = tid >> 2, sg = tid & 3;
  int n_g = nb*64 + sn;
  int b0 = n_g >> 10, pix0 = n_g & 1023, y0 = pix0 >> 5, x0 = pix0 & 31;
  const u16* bsrc = xrTp + (((size_t)(b0*1156 + (y0+1)*34 + x0+1))<<8) + sg*16;
  f4 acc[4];
  #pragma unroll
  for (int i=0;i<4;i++) acc[i] = (f4){0.f,0.f,0.f,0.f};
  const u16* arow = wkv + (size_t)(mb*64 + wv*16 + c15)*256 + quad*8;
  us8 cv0 = *(const us8*)bsrc, cv1 = *(const us8*)(bsrc + 8);
  int pb = 0;
  for (int kt = 0; kt < 4; ++kt) {
    u16* Bw = Blds + pb*4608;
    *(us8*)(Bw + sn*72 + sg*16) = cv0;
    *(us8*)(Bw + sn*72 + sg*16 + 8) = cv1;
    __syncthreads();
    if (kt < 3) { cv0 = *(const us8*)(bsrc + (kt+1)*64); cv1 = *(const us8*)(bsrc + (kt+1)*64 + 8); }
    s8v a0 = *(const s8v*)(arow + kt*64);
    s8v a1 = *(const s8v*)(arow + kt*64 + 32);
    #pragma unroll
    for (int t4=0;t4<4;t4++) {
      const u16* br = Blds + pb*4608 + (t4*16 + c15)*72 + quad*8;
      s8v bf0 = *(const s8v*)br;
      s8v bf1 = *(const s8v*)(br + 32);
      acc[t4] = __builtin_amdgcn_mfma_f32_16x16x32_bf16(a0, bf0, acc[t4], 0, 0, 0);
      acc[t4] = __builtin_amdgcn_mfma_f32_16x16x32_bf16(a1, bf1, acc[t4], 0, 0, 0);
    }
    pb ^= 1;
  }
  int ml = wv*16 + quad*4;
  #pragma unroll
  for (int t4=0;t4<4;t4++) {
    int n2 = nb*64 + t4*16 + c15;
    int b = n2 >> 10, pix = n2 & 1023;
    if (mb == 0) {
      int h = ml >> 3, d0 = ml & 7;
      u16 pk[4];
      #pragma unroll
      for (int rg=0; rg<4; rg++) pk[rg] = f2h(acc[t4][rg]);
      *(uint2*)(kT + ((size_t)(b*8+h)<<13) + pix*8 + d0) = *(uint2*)pk;
    } else {
      #pragma unroll
      for (int rg=0; rg<4; rg++)
        vbuf[(((size_t)(b*64 + ml + rg))<<10) + pix] = f2h(acc[t4][rg]);
    }
  }
}

// =================== K3: attention (no-max softmax, 1 pass) ===================
__global__ __launch_bounds__(256) void k_attn(
    const u16* __restrict__ qh, const u16* __restrict__ kT, const u16* __restrict__ vbuf,
    u16* __restrict__ attT)
{
  __shared__ __align__(16) u16 KL[8192];
  __shared__ __align__(16) u16 VL[9*1032];
  int qt = blockIdx.x, bh = blockIdx.y;
  int b = bh >> 3, h = bh & 7;
  int tid = threadIdx.x, lane = tid & 63, wv = tid >> 6, quad = lane >> 4, c15 = lane & 15;
  {
    const uint4* kg = (const uint4*)(kT + ((size_t)bh << 13));
    for (int i = tid; i < 1024; i += 256) ((uint4*)KL)[i] = kg[i];
    const u16* vg = vbuf + ((size_t)(b*64 + h*8) << 10);
    for (int i = tid; i < 1024; i += 256) {
      int dv = i >> 7, k8 = (i & 127) << 3;
      *(uint4*)(VL + dv*1032 + k8) = *(const uint4*)(vg + (dv<<10) + k8);
    }
    if (tid < 129) {
      us8 ones;
      #pragma unroll
      for (int i=0;i<8;i++) ones[i] = 0x3C00;
      *(us8*)(VL + 8*1032 + tid*8) = ones;
    }
  }
  __syncthreads();
  int q0 = qt*128 + wv*32 + c15;
  int q1 = q0 + 16;
  int qa = q0 < 4224 ? q0 : 4224;
  int qb = q1 < 4224 ? q1 : 4224;
  uint2 t0 = *(const uint2*)(qh + (((size_t)(b*4225 + qa))<<6) + h*8 + (quad&1)*4);
  uint2 t1 = *(const uint2*)(qh + (((size_t)(b*4225 + qb))<<6) + h*8 + (quad&1)*4);
  h4 bq0 = quad < 2 ? *(h4*)&t0 : (h4)(_Float16)0.f;
  h4 bq1 = quad < 2 ? *(h4*)&t1 : (h4)(_Float16)0.f;
  const u16* klb = KL + c15*8 + (quad&1)*4;
  int vr = c15 > 8 ? 8 : c15;
  const u16* vlb = VL + vr*1032 + quad*4;
  const f4 zf = {0.f,0.f,0.f,0.f};
  f4 O0 = {0.f,0.f,0.f,0.f}, O1 = {0.f,0.f,0.f,0.f};
  union HU { uint2 u; h4 h; };
  #pragma unroll 8
  for (int kt=0; kt<64; ++kt) {
    h4 ak = *(const h4*)(klb + kt*128);
    h4 av = *(const h4*)(vlb + kt*16);
    f4 s0 = __builtin_amdgcn_mfma_f32_16x16x16f16(ak, bq0, zf, 0, 0, 0);
    f4 s1 = __builtin_amdgcn_mfma_f32_16x16x16f16(ak, bq1, zf, 0, 0, 0);
    g2 p0l = __builtin_amdgcn_cvt_pkrtz(__builtin_amdgcn_exp2f(s0[0]), __builtin_amdgcn_exp2f(s0[1]));
    g2 p0h = __builtin_amdgcn_cvt_pkrtz(__builtin_amdgcn_exp2f(s0[2]), __builtin_amdgcn_exp2f(s0[3]));
    g2 p1l = __builtin_amdgcn_cvt_pkrtz(__builtin_amdgcn_exp2f(s1[0]), __builtin_amdgcn_exp2f(s1[1]));
    g2 p1h = __builtin_amdgcn_cvt_pkrtz(__builtin_amdgcn_exp2f(s1[2]), __builtin_amdgcn_exp2f(s1[3]));
    HU u0; u0.u.x = __builtin_bit_cast(u32, p0l); u0.u.y = __builtin_bit_cast(u32, p0h);
    HU u1; u1.u.x = __builtin_bit_cast(u32, p1l); u1.u.y = __builtin_bit_cast(u32, p1h);
    O0 = __builtin_amdgcn_mfma_f32_16x16x16f16(av, u0.h, O0, 0, 0, 0);
    O1 = __builtin_amdgcn_mfma_f32_16x16x16f16(av, u1.h, O1, 0, 0, 0);
  }
  float l0 = __shfl(O0[0], 32 + c15, 64);
  float l1 = __shfl(O1[0], 32 + c15, 64);
  float r0 = __builtin_amdgcn_rcpf(l0);
  float r1 = __builtin_amdgcn_rcpf(l1);
  if (quad < 2) {
    if (q0 < 4225) {
      u16 pk[4];
      #pragma unroll
      for (int rg=0;rg<4;rg++) pk[rg] = f2bf(O0[rg]*r0);
      *(uint2*)(attT + (((size_t)(b*4225 + q0))<<6) + h*8 + quad*4) = *(uint2*)pk;
    }
    if (q1 < 4225) {
      u16 pk[4];
      #pragma unroll
      for (int rg=0;rg<4;rg++) pk[rg] = f2bf(O1[rg]*r1);
      *(uint2*)(attT + (((size_t)(b*4225 + q1))<<6) + h*8 + quad*4) = *(uint2*)pk;
    }
  }
}

// =================== K4: output projection GEMM (no LDS) + shortcut add ===================
__global__ __launch_bounds__(256) void k_proj(
    const u16* __restrict__ attT, const u16* __restrict__ wo2, float* __restrict__ outF)
{
  int nbi = blockIdx.x, b = blockIdx.y;
  int tid = threadIdx.x;
  int lane = tid & 63, wv = tid >> 6, quad = lane >> 4, c15 = lane & 15;
  f4 acc[2][4];
  #pragma unroll
  for (int am=0;am<2;am++)
    #pragma unroll
    for (int i=0;i<4;i++) acc[am][i] = (f4){0.f,0.f,0.f,0.f};
  #pragma unroll
  for (int kt = 0; kt < 2; ++kt) {
    s8v a0 = *(const s8v*)(wo2 + (size_t)(wv*32 + c15)*64 + kt*32 + quad*8);
    s8v a1 = *(const s8v*)(wo2 + (size_t)(wv*32 + 16 + c15)*64 + kt*32 + quad*8);
    #pragma unroll
    for (int t4=0;t4<4;t4++) {
      int n = nbi*64 + t4*16 + c15;
      int nc = n < 4224 ? n : 4224;
      s8v bf = *(const s8v*)(attT + (((size_t)(b*4225 + nc))<<6) + kt*32 + quad*8);
      acc[0][t4] = __builtin_amdgcn_mfma_f32_16x16x32_bf16(a0, bf, acc[0][t4], 0, 0, 0);
      acc[1][t4] = __builtin_amdgcn_mfma_f32_16x16x32_bf16(a1, bf, acc[1][t4], 0, 0, 0);
    }
  }
  #pragma unroll
  for (int am=0;am<2;am++) {
    int mrow = wv*32 + am*16 + quad*4;
    #pragma unroll
    for (int t4=0;t4<4;t4++) {
      int n2 = nbi*64 + t4*16 + c15;
      if (n2 < 4225) {
        float* op = outF + (size_t)(b*128 + mrow)*4225 + n2;
        #pragma unroll
        for (int rg=0; rg<4; rg++) op[(size_t)rg*4225] += acc[am][t4][rg];
      }
    }
  }
}

extern "C" void kernel_launch(void* const* d_in, const int* in_sizes, int n_in,
                              void* d_out, int out_size, void* d_ws, size_t ws_size,
                              hipStream_t stream) {
  const float* x     = (const float*)d_in[0];
  const float* gamma = (const float*)d_in[1];
  const float* beta  = (const float*)d_in[2];
  const float* mean  = (const float*)d_in[3];
  const float* var   = (const float*)d_in[4];
  const float* w_sc  = (const float*)d_in[5];
  const float* w_q   = (const float*)d_in[6];
  const float* w_k   = (const float*)d_in[7];
  const float* w_v   = (const float*)d_in[8];
  const float* w_o   = (const float*)d_in[9];
  char* ws = (char*)d_ws;
  u16*   xrTp = (u16*)(ws + O_XRT);
  u16*   wpt  = (u16*)(ws + O_WPT);
  u16*   qhb  = (u16*)(ws + O_QH);
  u16*   kT   = (u16*)(ws + O_KT);
  u16*   vbuf = (u16*)(ws + O_V);
  u16*   attT = (u16*)(ws + O_ATT);
  u16*   wkv  = (u16*)(ws + O_WKV);
  u16*   wo2  = (u16*)(ws + O_WO2);
  float* outF = (float*)d_out;

  k_prep<<<2211, 256, 0, stream>>>(x, gamma, beta, mean, var, w_sc, w_q, w_k, w_v, w_o,
                                   xrTp, wpt, wkv, wo2);
  k_conv<<<923, 256, 0, stream>>>(xrTp, wpt, wkv, outF, qhb, kT, vbuf);
  k_attn<<<dim3(34, 32), 256, 0, stream>>>(qhb, kT, vbuf, attT);
  k_proj<<<dim3(67, 4), 256, 0, stream>>>(attT, wo2, outF);
}